// Round 7
// baseline (134.678 us; speedup 1.0000x reference)
//
#include <hip/hip_runtime.h>
#include <hip/hip_bf16.h>

// GCLSTM with H=C=None collapses to: gates from x@Wx only (conv = bconv const),
// forget gate dead, graph unused.
//   h1 = sig(zo)*tanh(sig(zi)*tanh(zc)),  z = x@Wx1[:,{i,c,o}] + bias
//   h2 = same with Wx2; out = relu(h2)@Wl + bl
//
// R7 vs R6 (R6 main ~30us inferred; latency-bound: R5 showed 85% no-issue
// cycles at 8 waves/CU, plus 106/2048 waves ran a 4th grid-stride iteration):
//  - 1 wave = 1 tile, NO loop: grid 1563 blocks x 4 waves = 6252 waves for
//    6250 tiles. Dynamic block scheduling balances; tail = one short block.
//  - LDS cut to 51.0 KB (B2 frags read from L2 per wave - no in-wave reuse)
//    -> 3 blocks/CU = 12 waves/CU, +50% TLP over R6.
//  - x consumed stage-by-stage (no 32-reg prefetch buffer): VGPR ~100.
//  - sched_barrier(0) between GEMM1 k-stages kept (R6's anti-spill guard).

#define NODES 100000
#define NTILES 6250

typedef float v4f   __attribute__((ext_vector_type(4)));
typedef float fragC __attribute__((ext_vector_type(4)));
typedef short frag8 __attribute__((ext_vector_type(8)));

// ws byte offsets
#define OFF_B1H 0       // 40 frags * 1024 B
#define OFF_B2H 40960   // 8 frags * 1024 B
#define OFF_PB1 49152   // 160 f32 packed-col biases (layer1)
#define OFF_PB2 49792   // 64 f32 packed-col biases (layer2)

__device__ __forceinline__ unsigned short f2bf(float f) {
  unsigned int u = __float_as_uint(f);
  u += 0x7fffu + ((u >> 16) & 1u);  // RNE
  return (unsigned short)(u >> 16);
}
__device__ __forceinline__ float fsig(float z) {
  float t = __builtin_amdgcn_exp2f(z * -1.44269504088896f);
  return __builtin_amdgcn_rcpf(1.0f + t);
}
__device__ __forceinline__ float ftanh(float z) {
  float t = __builtin_amdgcn_exp2f(z * 2.88539008177793f);
  return 1.0f - 2.0f * __builtin_amdgcn_rcpf(t + 1.0f);
}

union bfu { __hip_bfloat162 h; unsigned int u; };

__device__ __forceinline__ void cvt8(const float* v, frag8& hi, frag8& lo) {
  float lof[8];
#pragma unroll
  for (int p = 0; p < 4; ++p) {
    bfu c; c.h = __float22bfloat162_rn(make_float2(v[2 * p], v[2 * p + 1]));
    hi[2 * p]     = (short)(c.u & 0xffffu);
    hi[2 * p + 1] = (short)(c.u >> 16);
    lof[2 * p]     = v[2 * p]     - __uint_as_float((c.u & 0xffffu) << 16);
    lof[2 * p + 1] = v[2 * p + 1] - __uint_as_float(c.u & 0xffff0000u);
  }
#pragma unroll
  for (int p = 0; p < 4; ++p) {
    bfu c; c.h = __float22bfloat162_rn(make_float2(lof[2 * p], lof[2 * p + 1]));
    lo[2 * p]     = (short)(c.u & 0xffffu);
    lo[2 * p + 1] = (short)(c.u >> 16);
  }
}

// B1 packed-col: col = 16t+m.  t<=8: g=t%3, c=16*(t/3)+m.
// t==9: m<6 -> c=48+m/3, g=m%3; else pad.  g {i,c,o} -> Wx1 col {0,2,3}.
// B2 packed-col: col = 16t+m.  t<=2: g=t, c=m.
// t==3: m<12 -> c=16+m/3, g=m%3; else pad.  g -> Wx2 col {0,2,3}.
__global__ void pack_weights(const float* __restrict__ Wx1, const float* __restrict__ bx1,
                             const float* __restrict__ bconv1,
                             const float* __restrict__ Wx2, const float* __restrict__ bx2,
                             const float* __restrict__ bconv2,
                             unsigned char* __restrict__ ws) {
  const int tid = blockIdx.x * blockDim.x + threadIdx.x;
  const int stride = gridDim.x * blockDim.x;
  unsigned short* B1H = (unsigned short*)(ws + OFF_B1H);
  unsigned short* B2H = (unsigned short*)(ws + OFF_B2H);
  float* PB1 = (float*)(ws + OFF_PB1);
  float* PB2 = (float*)(ws + OFF_PB2);

  for (int idx = tid; idx < 20480; idx += stride) {
    int j = idx & 7, lane = (idx >> 3) & 63, ft = idx >> 9;  // ft = s*10+t
    int s = ft / 10, t = ft % 10;
    int k = 32 * s + ((lane >> 4) << 3) + j;
    int m = lane & 15;
    int c = -1, g = 0;
    if (t <= 8) { g = t % 3; c = 16 * (t / 3) + m; }
    else if (m < 6) { c = 48 + m / 3; g = m % 3; }
    float val = 0.f;
    if (c >= 0) {
      int gs = (g == 0) ? 0 : (g == 1) ? 2 : 3;
      val = Wx1[k * 200 + gs * 50 + c];
    }
    B1H[idx] = f2bf(val);
  }
  for (int idx = tid; idx < 4096; idx += stride) {
    int j = idx & 7, lane = (idx >> 3) & 63, ft = idx >> 9;  // ft = s*4+t
    int s = ft >> 2, t = ft & 3;
    int k = 32 * s + ((lane >> 4) << 3) + j;
    int m = lane & 15;
    int c = -1, g = 0;
    if (t <= 2) { g = t; c = m; }
    else if (m < 12) { c = 16 + m / 3; g = m % 3; }
    float val = 0.f;
    if (c >= 0 && k < 50) {
      int gs = (g == 0) ? 0 : (g == 1) ? 2 : 3;
      val = Wx2[k * 80 + gs * 20 + c];
    }
    B2H[idx] = f2bf(val);
  }
  for (int idx = tid; idx < 160; idx += stride) {
    int t = idx >> 4, m = idx & 15;
    int c = -1, g = 0;
    if (t <= 8) { g = t % 3; c = 16 * (t / 3) + m; }
    else if (m < 6) { c = 48 + m / 3; g = m % 3; }
    float v = 0.f;
    if (c >= 0) {
      int gs = (g == 0) ? 0 : (g == 1) ? 2 : 3;
      v = bx1[gs * 50 + c] + bconv1[gs * 50 + c];
    }
    PB1[idx] = v;
  }
  for (int idx = tid; idx < 64; idx += stride) {
    int t = idx >> 4, m = idx & 15;
    int c = -1, g = 0;
    if (t <= 2) { g = t; c = m; }
    else if (m < 12) { c = 16 + m / 3; g = m % 3; }
    float v = 0.f;
    if (c >= 0) {
      int gs = (g == 0) ? 0 : (g == 1) ? 2 : 3;
      v = bx2[gs * 20 + c] + bconv2[gs * 20 + c];
    }
    PB2[idx] = v;
  }
}

__global__ __launch_bounds__(256) void gclstm_main(
    const float* __restrict__ x, const unsigned char* __restrict__ wsb,
    const float* __restrict__ Wl, const float* __restrict__ bl,
    float* __restrict__ out) {
  __shared__ short sB1[20480];                  // 40960 B: B1 fragments (bf16)
  __shared__ unsigned short sH[4][16 * 72];     //  9216 B: per-wave h1 (bf16)
  __shared__ float sPB1[160];                   // packed-col biases L1
  __shared__ float sPB2[64];                    // packed-col biases L2
  // total 51072 B -> 3 blocks/CU, 12 waves/CU

  const int tid = threadIdx.x;
  const int lane = tid & 63;
  const int wave = tid >> 6;
  const int m = lane & 15;
  const int q = lane >> 4;
  const int tau = blockIdx.x * 4 + wave;  // this wave's tile

  {  // stage B1 + biases -> LDS; zero h scratch (K-pad cols)
    const v4f* g1 = (const v4f*)(wsb + OFF_B1H);
    v4f* s1 = (v4f*)sB1;
    for (int i = tid; i < 2560; i += 256) s1[i] = g1[i];
    const float* p1 = (const float*)(wsb + OFF_PB1);
    if (tid < 160) sPB1[tid] = p1[tid];
    const float* p2 = (const float*)(wsb + OFF_PB2);
    if (tid < 64) sPB2[tid] = p2[tid];
    unsigned int* hz = (unsigned int*)sH;
    for (int i = tid; i < 2304; i += 256) hz[i] = 0u;
  }
  __syncthreads();

  if (tau >= NTILES) return;  // only waves 6250,6251 of the last block

  unsigned short* sHw = (unsigned short*)sH + wave * (16 * 72);
  const frag8* sB1f = (const frag8*)sB1;

  // x rows: lane m -> row, quad q -> k-octet base
  const float* xr = x + (size_t)(tau * 16 + m) * 128 + q * 8;
  v4f xb[8];
#pragma unroll
  for (int s = 0; s < 4; ++s) {
    xb[2 * s] = *(const v4f*)(xr + 32 * s);
    xb[2 * s + 1] = *(const v4f*)(xr + 32 * s + 4);
  }

  // ---- GEMM1: z1[16 x 160] = A(hi+lo) @ B1h, bias in acc init ----
  fragC acc[10];
#pragma unroll
  for (int t = 0; t < 10; ++t) {
    float bv = sPB1[16 * t + m];
    acc[t] = (fragC){bv, bv, bv, bv};
  }
#pragma unroll
  for (int s = 0; s < 4; ++s) {
    float av[8];
    *(v4f*)av = xb[2 * s];
    *(v4f*)(av + 4) = xb[2 * s + 1];
    frag8 ah, al;
    cvt8(av, ah, al);
#pragma unroll
    for (int t = 0; t < 10; ++t) {
      frag8 b = sB1f[(s * 10 + t) * 64 + lane];
      acc[t] = __builtin_amdgcn_mfma_f32_16x16x32_bf16(ah, b, acc[t], 0, 0, 0);
      acc[t] = __builtin_amdgcn_mfma_f32_16x16x32_bf16(al, b, acc[t], 0, 0, 0);
    }
    // cap B-frag/load hoisting to one k-stage (R4/R5's spill storm was the
    // scheduler lifting all 40 frags = 160 VGPRs)
    __builtin_amdgcn_sched_barrier(0);
  }

  // gates from registers (packed-col): lane (m,q) -> rows 4q+r, channel 16b+m
#pragma unroll
  for (int b = 0; b < 3; ++b)
#pragma unroll
    for (int r = 0; r < 4; ++r) {
      float I = fsig(acc[3 * b][r]);
      float T = ftanh(acc[3 * b + 1][r]);
      float O = fsig(acc[3 * b + 2][r]);
      sHw[(q * 4 + r) * 72 + 16 * b + m] = f2bf(O * ftanh(I * T));
    }
  // channels 48,49 from acc[9] via shfl: c48 lanes 16q+{0,1,2}, c49 +{3,4,5}
#pragma unroll
  for (int r = 0; r < 4; ++r) {
    float vI = __shfl(acc[9][r], 16 * q + m);
    float vT = __shfl(acc[9][r], 16 * q + m + 1);
    float vO = __shfl(acc[9][r], 16 * q + m + 2);
    if (m == 0 || m == 3) {
      float I = fsig(vI), T = ftanh(vT), O = fsig(vO);
      sHw[(q * 4 + r) * 72 + 48 + (m >> 1)] = f2bf(O * ftanh(I * T));
    }
  }

  // ---- GEMM2: z2[16 x 64] = h1(bf16) @ B2h (frags from L2), K padded ----
  const frag8* g2 = (const frag8*)(wsb + OFF_B2H);
  frag8 hh[2];
#pragma unroll
  for (int s = 0; s < 2; ++s)
    hh[s] = *(const frag8*)(sHw + m * 72 + 32 * s + 8 * q);
  fragC acc2[4];
#pragma unroll
  for (int t = 0; t < 4; ++t) {
    float bv = sPB2[16 * t + m];
    acc2[t] = (fragC){bv, bv, bv, bv};
  }
#pragma unroll
  for (int s = 0; s < 2; ++s)
#pragma unroll
    for (int t = 0; t < 4; ++t) {
      frag8 b = g2[(s * 4 + t) * 64 + lane];
      acc2[t] = __builtin_amdgcn_mfma_f32_16x16x32_bf16(hh[s], b, acc2[t], 0, 0, 0);
    }

  // epilogue in registers: lane owns ch m (t=0,1,2) and (m<4) ch 16+m via shfl
  const float wlm = Wl[m];
  const float wlx = (m < 4) ? Wl[16 + m] : 0.f;
  const float blv = bl[0];
  v4f res;
#pragma unroll
  for (int r = 0; r < 4; ++r) {
    float I = fsig(acc2[0][r]);
    float T = ftanh(acc2[1][r]);
    float O = fsig(acc2[2][r]);
    float h2 = O * ftanh(I * T);
    float part = fmaxf(h2, 0.f) * wlm;
    float eI = __shfl(acc2[3][r], 16 * q + 3 * m);
    float eT = __shfl(acc2[3][r], 16 * q + 3 * m + 1);
    float eO = __shfl(acc2[3][r], 16 * q + 3 * m + 2);
    float I2 = fsig(eI), T2 = ftanh(eT), O2 = fsig(eO);
    float h2x = O2 * ftanh(I2 * T2);
    part += fmaxf(h2x, 0.f) * wlx;
    part += __shfl_xor(part, 1);
    part += __shfl_xor(part, 2);
    part += __shfl_xor(part, 4);
    part += __shfl_xor(part, 8);
    res[r] = part + blv;
  }
  if (m == 0) *(v4f*)(out + tau * 16 + 4 * q) = res;
}

extern "C" void kernel_launch(void* const* d_in, const int* in_sizes, int n_in,
                              void* d_out, int out_size, void* d_ws, size_t ws_size,
                              hipStream_t stream) {
  (void)in_sizes; (void)n_in; (void)out_size; (void)ws_size;
  const float* x = (const float*)d_in[0];
  // d_in[1] edge_index, d_in[2] edge_weight, d_in[5] theta1, d_in[9] theta2: dead
  const float* Wx1 = (const float*)d_in[3];
  const float* bx1 = (const float*)d_in[4];
  const float* bconv1 = (const float*)d_in[6];
  const float* Wx2 = (const float*)d_in[7];
  const float* bx2 = (const float*)d_in[8];
  const float* bconv2 = (const float*)d_in[10];
  const float* Wl = (const float*)d_in[11];
  const float* bl = (const float*)d_in[12];
  unsigned char* ws = (unsigned char*)d_ws;  // needs ~50 KB

  hipLaunchKernelGGL(pack_weights, dim3(32), dim3(256), 0, stream,
                     Wx1, bx1, bconv1, Wx2, bx2, bconv2, ws);
  hipLaunchKernelGGL(gclstm_main, dim3((NTILES + 3) / 4), dim3(256), 0, stream,
                     x, ws, Wl, bl, (float*)d_out);
}

// Round 8
// 132.547 us; speedup vs baseline: 1.0161x; 1.0161x over previous
//
#include <hip/hip_runtime.h>
#include <hip/hip_bf16.h>

// GCLSTM with H=C=None collapses to: gates from x@Wx only (conv = bconv const),
// forget gate dead, graph unused.
//   h1 = sig(zo)*tanh(sig(zi)*tanh(zc)),  z = x@Wx1[:,{i,c,o}] + bias
//   h2 = same with Wx2; out = relu(h2)@Wl + bl
//
// R8 vs R7 (R6==R7 ~30us main despite +50% TLP -> not wave-count-bound; the
// common serial prologue was 40KB B1 LDS staging + barrier per block, and
// ds_read B-frag latency in a one-shot kernel):
//  - B1/B2 fragments read DIRECTLY from L2 (global dwordx4): 40KB ws region is
//    L2-resident per XCD; ~256 MB aggregate L2 reads ~ 7.4us, overlaps the
//    8us x HBM stream. No staging loop, no __syncthreads at all.
//  - LDS = 9.2 KB (per-wave h1 transpose buffer only); biases/Wl per-lane L2.
//  - launch_bounds(256,3) (VGPR cap 170, peak ~145 - no spill) ;
//    sched_barrier(0) per GEMM1 k-stage caps B-frag hoisting at 10 frags.

#define NODES 100000
#define NTILES 6250

typedef float v4f   __attribute__((ext_vector_type(4)));
typedef float fragC __attribute__((ext_vector_type(4)));
typedef short frag8 __attribute__((ext_vector_type(8)));

// ws byte offsets
#define OFF_B1H 0       // 40 frags * 1024 B
#define OFF_B2H 40960   // 8 frags * 1024 B
#define OFF_PB1 49152   // 160 f32 packed-col biases (layer1)
#define OFF_PB2 49792   // 64 f32 packed-col biases (layer2)

__device__ __forceinline__ unsigned short f2bf(float f) {
  unsigned int u = __float_as_uint(f);
  u += 0x7fffu + ((u >> 16) & 1u);  // RNE
  return (unsigned short)(u >> 16);
}
__device__ __forceinline__ float fsig(float z) {
  float t = __builtin_amdgcn_exp2f(z * -1.44269504088896f);
  return __builtin_amdgcn_rcpf(1.0f + t);
}
__device__ __forceinline__ float ftanh(float z) {
  float t = __builtin_amdgcn_exp2f(z * 2.88539008177793f);
  return 1.0f - 2.0f * __builtin_amdgcn_rcpf(t + 1.0f);
}

union bfu { __hip_bfloat162 h; unsigned int u; };

__device__ __forceinline__ void cvt8(const float* v, frag8& hi, frag8& lo) {
  float lof[8];
#pragma unroll
  for (int p = 0; p < 4; ++p) {
    bfu c; c.h = __float22bfloat162_rn(make_float2(v[2 * p], v[2 * p + 1]));
    hi[2 * p]     = (short)(c.u & 0xffffu);
    hi[2 * p + 1] = (short)(c.u >> 16);
    lof[2 * p]     = v[2 * p]     - __uint_as_float((c.u & 0xffffu) << 16);
    lof[2 * p + 1] = v[2 * p + 1] - __uint_as_float(c.u & 0xffff0000u);
  }
#pragma unroll
  for (int p = 0; p < 4; ++p) {
    bfu c; c.h = __float22bfloat162_rn(make_float2(lof[2 * p], lof[2 * p + 1]));
    lo[2 * p]     = (short)(c.u & 0xffffu);
    lo[2 * p + 1] = (short)(c.u >> 16);
  }
}

// B1 packed-col: col = 16t+m.  t<=8: g=t%3, c=16*(t/3)+m.
// t==9: m<6 -> c=48+m/3, g=m%3; else pad.  g {i,c,o} -> Wx1 col {0,2,3}.
// B2 packed-col: col = 16t+m.  t<=2: g=t, c=m.
// t==3: m<12 -> c=16+m/3, g=m%3; else pad.  g -> Wx2 col {0,2,3}.
__global__ void pack_weights(const float* __restrict__ Wx1, const float* __restrict__ bx1,
                             const float* __restrict__ bconv1,
                             const float* __restrict__ Wx2, const float* __restrict__ bx2,
                             const float* __restrict__ bconv2,
                             unsigned char* __restrict__ ws) {
  const int tid = blockIdx.x * blockDim.x + threadIdx.x;
  const int stride = gridDim.x * blockDim.x;
  unsigned short* B1H = (unsigned short*)(ws + OFF_B1H);
  unsigned short* B2H = (unsigned short*)(ws + OFF_B2H);
  float* PB1 = (float*)(ws + OFF_PB1);
  float* PB2 = (float*)(ws + OFF_PB2);

  for (int idx = tid; idx < 20480; idx += stride) {
    int j = idx & 7, lane = (idx >> 3) & 63, ft = idx >> 9;  // ft = s*10+t
    int s = ft / 10, t = ft % 10;
    int k = 32 * s + ((lane >> 4) << 3) + j;
    int m = lane & 15;
    int c = -1, g = 0;
    if (t <= 8) { g = t % 3; c = 16 * (t / 3) + m; }
    else if (m < 6) { c = 48 + m / 3; g = m % 3; }
    float val = 0.f;
    if (c >= 0) {
      int gs = (g == 0) ? 0 : (g == 1) ? 2 : 3;
      val = Wx1[k * 200 + gs * 50 + c];
    }
    B1H[idx] = f2bf(val);
  }
  for (int idx = tid; idx < 4096; idx += stride) {
    int j = idx & 7, lane = (idx >> 3) & 63, ft = idx >> 9;  // ft = s*4+t
    int s = ft >> 2, t = ft & 3;
    int k = 32 * s + ((lane >> 4) << 3) + j;
    int m = lane & 15;
    int c = -1, g = 0;
    if (t <= 2) { g = t; c = m; }
    else if (m < 12) { c = 16 + m / 3; g = m % 3; }
    float val = 0.f;
    if (c >= 0 && k < 50) {
      int gs = (g == 0) ? 0 : (g == 1) ? 2 : 3;
      val = Wx2[k * 80 + gs * 20 + c];
    }
    B2H[idx] = f2bf(val);
  }
  for (int idx = tid; idx < 160; idx += stride) {
    int t = idx >> 4, m = idx & 15;
    int c = -1, g = 0;
    if (t <= 8) { g = t % 3; c = 16 * (t / 3) + m; }
    else if (m < 6) { c = 48 + m / 3; g = m % 3; }
    float v = 0.f;
    if (c >= 0) {
      int gs = (g == 0) ? 0 : (g == 1) ? 2 : 3;
      v = bx1[gs * 50 + c] + bconv1[gs * 50 + c];
    }
    PB1[idx] = v;
  }
  for (int idx = tid; idx < 64; idx += stride) {
    int t = idx >> 4, m = idx & 15;
    int c = -1, g = 0;
    if (t <= 2) { g = t; c = m; }
    else if (m < 12) { c = 16 + m / 3; g = m % 3; }
    float v = 0.f;
    if (c >= 0) {
      int gs = (g == 0) ? 0 : (g == 1) ? 2 : 3;
      v = bx2[gs * 20 + c] + bconv2[gs * 20 + c];
    }
    PB2[idx] = v;
  }
}

__global__ __launch_bounds__(256, 3) void gclstm_main(
    const float* __restrict__ x, const unsigned char* __restrict__ wsb,
    const float* __restrict__ Wl, const float* __restrict__ bl,
    float* __restrict__ out) {
  __shared__ unsigned short sH[4][16 * 72];  // 9216 B: per-wave h1 (bf16)

  const int tid = threadIdx.x;
  const int lane = tid & 63;
  const int wave = tid >> 6;
  const int m = lane & 15;
  const int q = lane >> 4;
  const int tau = blockIdx.x * 4 + wave;  // this wave's tile
  if (tau >= NTILES) return;              // no barriers anywhere -> safe

  unsigned short* sHw = (unsigned short*)sH + wave * (16 * 72);

  // zero K-pad cols 48..63 of this wave's h1 buffer (cols 48,49 overwritten
  // by gates below; 50..63 must be 0 for GEMM2's padded K)
  {
    int r0 = lane >> 2, c0 = 48 + (lane & 3) * 4;
    *(unsigned long long*)(sHw + r0 * 72 + c0) = 0ull;
  }

  // per-lane biases from L2 (packed-col order)
  const float* pb1 = (const float*)(wsb + OFF_PB1);
  const float* pb2 = (const float*)(wsb + OFF_PB2);
  float bias1v[10], bias2v[4];
#pragma unroll
  for (int t = 0; t < 10; ++t) bias1v[t] = pb1[16 * t + m];
#pragma unroll
  for (int t = 0; t < 4; ++t) bias2v[t] = pb2[16 * t + m];

  // x rows: lane m -> row, quad q -> k-octet base
  const float* xr = x + (size_t)(tau * 16 + m) * 128 + q * 8;
  v4f xb[8];
#pragma unroll
  for (int s = 0; s < 4; ++s) {
    xb[2 * s] = *(const v4f*)(xr + 32 * s);
    xb[2 * s + 1] = *(const v4f*)(xr + 32 * s + 4);
  }

  // ---- GEMM1: z1[16 x 160] = A(hi+lo) @ B1h, B frags straight from L2 ----
  const frag8* g1 = (const frag8*)(wsb + OFF_B1H);
  fragC acc[10];
#pragma unroll
  for (int t = 0; t < 10; ++t)
    acc[t] = (fragC){bias1v[t], bias1v[t], bias1v[t], bias1v[t]};
#pragma unroll
  for (int s = 0; s < 4; ++s) {
    float av[8];
    *(v4f*)av = xb[2 * s];
    *(v4f*)(av + 4) = xb[2 * s + 1];
    frag8 ah, al;
    cvt8(av, ah, al);
#pragma unroll
    for (int t = 0; t < 10; ++t) {
      frag8 b = g1[(s * 10 + t) * 64 + lane];
      acc[t] = __builtin_amdgcn_mfma_f32_16x16x32_bf16(ah, b, acc[t], 0, 0, 0);
      acc[t] = __builtin_amdgcn_mfma_f32_16x16x32_bf16(al, b, acc[t], 0, 0, 0);
    }
    // cap B-frag hoisting at one k-stage (10 frags = 40 VGPRs); without this
    // the scheduler lifts all 40 frags -> R4/R5's 100 MB/iter spill storm
    __builtin_amdgcn_sched_barrier(0);
  }

  // gates from registers (packed-col): lane (m,q) -> rows 4q+r, channel 16b+m
#pragma unroll
  for (int b = 0; b < 3; ++b)
#pragma unroll
    for (int r = 0; r < 4; ++r) {
      float I = fsig(acc[3 * b][r]);
      float T = ftanh(acc[3 * b + 1][r]);
      float O = fsig(acc[3 * b + 2][r]);
      sHw[(q * 4 + r) * 72 + 16 * b + m] = f2bf(O * ftanh(I * T));
    }
  // channels 48,49 from acc[9] via shfl: c48 lanes 16q+{0,1,2}, c49 +{3,4,5}
#pragma unroll
  for (int r = 0; r < 4; ++r) {
    float vI = __shfl(acc[9][r], 16 * q + m);
    float vT = __shfl(acc[9][r], 16 * q + m + 1);
    float vO = __shfl(acc[9][r], 16 * q + m + 2);
    if (m == 0 || m == 3) {
      float I = fsig(vI), T = ftanh(vT), O = fsig(vO);
      sHw[(q * 4 + r) * 72 + 48 + (m >> 1)] = f2bf(O * ftanh(I * T));
    }
  }

  // ---- GEMM2: z2[16 x 64] = h1(bf16) @ B2h (frags from L2), K padded ----
  const frag8* g2 = (const frag8*)(wsb + OFF_B2H);
  frag8 hh[2];
#pragma unroll
  for (int s = 0; s < 2; ++s)
    hh[s] = *(const frag8*)(sHw + m * 72 + 32 * s + 8 * q);
  fragC acc2[4];
#pragma unroll
  for (int t = 0; t < 4; ++t)
    acc2[t] = (fragC){bias2v[t], bias2v[t], bias2v[t], bias2v[t]};
#pragma unroll
  for (int s = 0; s < 2; ++s)
#pragma unroll
    for (int t = 0; t < 4; ++t) {
      frag8 b = g2[(s * 4 + t) * 64 + lane];
      acc2[t] = __builtin_amdgcn_mfma_f32_16x16x32_bf16(hh[s], b, acc2[t], 0, 0, 0);
    }

  // epilogue in registers: lane owns ch m (t=0,1,2) and (m<4) ch 16+m via shfl
  const float wlm = Wl[m];
  const float wlx = (m < 4) ? Wl[16 + m] : 0.f;
  const float blv = bl[0];
  v4f res;
#pragma unroll
  for (int r = 0; r < 4; ++r) {
    float I = fsig(acc2[0][r]);
    float T = ftanh(acc2[1][r]);
    float O = fsig(acc2[2][r]);
    float h2 = O * ftanh(I * T);
    float part = fmaxf(h2, 0.f) * wlm;
    float eI = __shfl(acc2[3][r], 16 * q + 3 * m);
    float eT = __shfl(acc2[3][r], 16 * q + 3 * m + 1);
    float eO = __shfl(acc2[3][r], 16 * q + 3 * m + 2);
    float I2 = fsig(eI), T2 = ftanh(eT), O2 = fsig(eO);
    float h2x = O2 * ftanh(I2 * T2);
    part += fmaxf(h2x, 0.f) * wlx;
    part += __shfl_xor(part, 1);
    part += __shfl_xor(part, 2);
    part += __shfl_xor(part, 4);
    part += __shfl_xor(part, 8);
    res[r] = part + blv;
  }
  if (m == 0) *(v4f*)(out + tau * 16 + 4 * q) = res;
}

extern "C" void kernel_launch(void* const* d_in, const int* in_sizes, int n_in,
                              void* d_out, int out_size, void* d_ws, size_t ws_size,
                              hipStream_t stream) {
  (void)in_sizes; (void)n_in; (void)out_size; (void)ws_size;
  const float* x = (const float*)d_in[0];
  // d_in[1] edge_index, d_in[2] edge_weight, d_in[5] theta1, d_in[9] theta2: dead
  const float* Wx1 = (const float*)d_in[3];
  const float* bx1 = (const float*)d_in[4];
  const float* bconv1 = (const float*)d_in[6];
  const float* Wx2 = (const float*)d_in[7];
  const float* bx2 = (const float*)d_in[8];
  const float* bconv2 = (const float*)d_in[10];
  const float* Wl = (const float*)d_in[11];
  const float* bl = (const float*)d_in[12];
  unsigned char* ws = (unsigned char*)d_ws;  // needs ~50 KB

  hipLaunchKernelGGL(pack_weights, dim3(32), dim3(256), 0, stream,
                     Wx1, bx1, bconv1, Wx2, bx2, bconv2, ws);
  hipLaunchKernelGGL(gclstm_main, dim3((NTILES + 3) / 4), dim3(256), 0, stream,
                     x, ws, Wl, bl, (float*)d_out);
}

// Round 9
// 129.726 us; speedup vs baseline: 1.0382x; 1.0218x over previous
//
#include <hip/hip_runtime.h>
#include <hip/hip_bf16.h>

// GCLSTM with H=C=None collapses to: gates from x@Wx only (conv = bconv const),
// forget gate dead, graph unused.
//   h1 = sig(zo)*tanh(sig(zi)*tanh(zc)),  z = x@Wx1[:,{i,c,o}] + bias
//   h2 = same with Wx2; out = relu(h2)@Wl + bl
//
// R9 vs R8 (R6/R7/R8 all ~132.5 total despite structural changes -> the
// remaining per-wave work itself is the only candidate left in-main):
//  - A in bf16-hi ONLY (no hi/lo split): GEMM1 80 -> 40 MFMAs, half the cvt.
//    Error: adds a source ~equal to B1-bf16's; expect absmax ~1e-3 < 1.8e-3.
//  - software-pipelined B-frag loads: two explicit 10-frag buffers, stage s+1
//    loads issue before stage s MFMAs; sched_barrier(0) at stage ends stops
//    the R4/R5 full-hoist spill storm. B2 frags load during gate VALU.
//  - launch_bounds(256,2): peak ~150 regs vs cap 256, zero spill risk.
// Discriminating experiment: if total stays ~132, the bench is harness-
// floored and main is already small -> roofline.

#define NODES 100000
#define NTILES 6250

typedef float v4f   __attribute__((ext_vector_type(4)));
typedef float fragC __attribute__((ext_vector_type(4)));
typedef short frag8 __attribute__((ext_vector_type(8)));

// ws byte offsets
#define OFF_B1H 0       // 40 frags * 1024 B
#define OFF_B2H 40960   // 8 frags * 1024 B
#define OFF_PB1 49152   // 160 f32 packed-col biases (layer1)
#define OFF_PB2 49792   // 64 f32 packed-col biases (layer2)

__device__ __forceinline__ unsigned short f2bf(float f) {
  unsigned int u = __float_as_uint(f);
  u += 0x7fffu + ((u >> 16) & 1u);  // RNE
  return (unsigned short)(u >> 16);
}
__device__ __forceinline__ float fsig(float z) {
  float t = __builtin_amdgcn_exp2f(z * -1.44269504088896f);
  return __builtin_amdgcn_rcpf(1.0f + t);
}
__device__ __forceinline__ float ftanh(float z) {
  float t = __builtin_amdgcn_exp2f(z * 2.88539008177793f);
  return 1.0f - 2.0f * __builtin_amdgcn_rcpf(t + 1.0f);
}

union bfu { __hip_bfloat162 h; unsigned int u; };

__device__ __forceinline__ frag8 cvt8hi(const float* v) {
  frag8 hi;
#pragma unroll
  for (int p = 0; p < 4; ++p) {
    bfu c; c.h = __float22bfloat162_rn(make_float2(v[2 * p], v[2 * p + 1]));
    hi[2 * p]     = (short)(c.u & 0xffffu);
    hi[2 * p + 1] = (short)(c.u >> 16);
  }
  return hi;
}

// B1 packed-col: col = 16t+m.  t<=8: g=t%3, c=16*(t/3)+m.
// t==9: m<6 -> c=48+m/3, g=m%3; else pad.  g {i,c,o} -> Wx1 col {0,2,3}.
// B2 packed-col: col = 16t+m.  t<=2: g=t, c=m.
// t==3: m<12 -> c=16+m/3, g=m%3; else pad.  g -> Wx2 col {0,2,3}.
__global__ void pack_weights(const float* __restrict__ Wx1, const float* __restrict__ bx1,
                             const float* __restrict__ bconv1,
                             const float* __restrict__ Wx2, const float* __restrict__ bx2,
                             const float* __restrict__ bconv2,
                             unsigned char* __restrict__ ws) {
  const int tid = blockIdx.x * blockDim.x + threadIdx.x;
  const int stride = gridDim.x * blockDim.x;
  unsigned short* B1H = (unsigned short*)(ws + OFF_B1H);
  unsigned short* B2H = (unsigned short*)(ws + OFF_B2H);
  float* PB1 = (float*)(ws + OFF_PB1);
  float* PB2 = (float*)(ws + OFF_PB2);

  for (int idx = tid; idx < 20480; idx += stride) {
    int j = idx & 7, lane = (idx >> 3) & 63, ft = idx >> 9;  // ft = s*10+t
    int s = ft / 10, t = ft % 10;
    int k = 32 * s + ((lane >> 4) << 3) + j;
    int m = lane & 15;
    int c = -1, g = 0;
    if (t <= 8) { g = t % 3; c = 16 * (t / 3) + m; }
    else if (m < 6) { c = 48 + m / 3; g = m % 3; }
    float val = 0.f;
    if (c >= 0) {
      int gs = (g == 0) ? 0 : (g == 1) ? 2 : 3;
      val = Wx1[k * 200 + gs * 50 + c];
    }
    B1H[idx] = f2bf(val);
  }
  for (int idx = tid; idx < 4096; idx += stride) {
    int j = idx & 7, lane = (idx >> 3) & 63, ft = idx >> 9;  // ft = s*4+t
    int s = ft >> 2, t = ft & 3;
    int k = 32 * s + ((lane >> 4) << 3) + j;
    int m = lane & 15;
    int c = -1, g = 0;
    if (t <= 2) { g = t; c = m; }
    else if (m < 12) { c = 16 + m / 3; g = m % 3; }
    float val = 0.f;
    if (c >= 0 && k < 50) {
      int gs = (g == 0) ? 0 : (g == 1) ? 2 : 3;
      val = Wx2[k * 80 + gs * 20 + c];
    }
    B2H[idx] = f2bf(val);
  }
  for (int idx = tid; idx < 160; idx += stride) {
    int t = idx >> 4, m = idx & 15;
    int c = -1, g = 0;
    if (t <= 8) { g = t % 3; c = 16 * (t / 3) + m; }
    else if (m < 6) { c = 48 + m / 3; g = m % 3; }
    float v = 0.f;
    if (c >= 0) {
      int gs = (g == 0) ? 0 : (g == 1) ? 2 : 3;
      v = bx1[gs * 50 + c] + bconv1[gs * 50 + c];
    }
    PB1[idx] = v;
  }
  for (int idx = tid; idx < 64; idx += stride) {
    int t = idx >> 4, m = idx & 15;
    int c = -1, g = 0;
    if (t <= 2) { g = t; c = m; }
    else if (m < 12) { c = 16 + m / 3; g = m % 3; }
    float v = 0.f;
    if (c >= 0) {
      int gs = (g == 0) ? 0 : (g == 1) ? 2 : 3;
      v = bx2[gs * 20 + c] + bconv2[gs * 20 + c];
    }
    PB2[idx] = v;
  }
}

__global__ __launch_bounds__(256, 2) void gclstm_main(
    const float* __restrict__ x, const unsigned char* __restrict__ wsb,
    const float* __restrict__ Wl, const float* __restrict__ bl,
    float* __restrict__ out) {
  __shared__ unsigned short sH[4][16 * 72];  // 9216 B: per-wave h1 (bf16)

  const int tid = threadIdx.x;
  const int lane = tid & 63;
  const int wave = tid >> 6;
  const int m = lane & 15;
  const int q = lane >> 4;
  const int tau = blockIdx.x * 4 + wave;  // this wave's tile
  if (tau >= NTILES) return;              // no barriers anywhere -> safe

  unsigned short* sHw = (unsigned short*)sH + wave * (16 * 72);

  // zero K-pad cols 48..63 of this wave's h1 rows (48,49 overwritten below)
  {
    int r0 = lane >> 2, c0 = 48 + (lane & 3) * 4;
    *(unsigned long long*)(sHw + r0 * 72 + c0) = 0ull;
  }

  // x rows: lane m -> row, quad q -> k-octet base (issue first, deepest miss)
  const float* xr = x + (size_t)(tau * 16 + m) * 128 + q * 8;
  v4f xb[8];
#pragma unroll
  for (int s = 0; s < 4; ++s) {
    xb[2 * s] = *(const v4f*)(xr + 32 * s);
    xb[2 * s + 1] = *(const v4f*)(xr + 32 * s + 4);
  }

  // per-lane biases from L2 (packed-col order)
  const float* pb1 = (const float*)(wsb + OFF_PB1);
  const float* pb2 = (const float*)(wsb + OFF_PB2);
  float bias1v[10], bias2v[4];
#pragma unroll
  for (int t = 0; t < 10; ++t) bias1v[t] = pb1[16 * t + m];
#pragma unroll
  for (int t = 0; t < 4; ++t) bias2v[t] = pb2[16 * t + m];

  const frag8* g1 = (const frag8*)(wsb + OFF_B1H);
  const frag8* g2 = (const frag8*)(wsb + OFF_B2H);

  // stage-0 B frags
  frag8 ba[10], bb[10];
#pragma unroll
  for (int t = 0; t < 10; ++t) ba[t] = g1[t * 64 + lane];

  // A -> bf16 (hi only)
  frag8 ah[4];
#pragma unroll
  for (int s = 0; s < 4; ++s) {
    float av[8];
    *(v4f*)av = xb[2 * s];
    *(v4f*)(av + 4) = xb[2 * s + 1];
    ah[s] = cvt8hi(av);
  }

  // ---- GEMM1: z1[16 x 160] = A @ B1, software-pipelined B double-buffer ----
  fragC acc[10];
#pragma unroll
  for (int t = 0; t < 10; ++t)
    acc[t] = (fragC){bias1v[t], bias1v[t], bias1v[t], bias1v[t]};
#pragma unroll
  for (int s = 0; s < 4; ++s) {
    frag8* bc = (s & 1) ? bb : ba;
    frag8* bn = (s & 1) ? ba : bb;
    if (s < 3) {  // issue next stage's loads ahead of this stage's MFMAs
#pragma unroll
      for (int t = 0; t < 10; ++t) bn[t] = g1[((s + 1) * 10 + t) * 64 + lane];
    }
#pragma unroll
    for (int t = 0; t < 10; ++t)
      acc[t] = __builtin_amdgcn_mfma_f32_16x16x32_bf16(ah[s], bc[t], acc[t], 0, 0, 0);
    // stage fence: caps hoisting at one extra buffer (2x40 frag regs max);
    // without it the scheduler lifts everything -> R4/R5's spill storm
    __builtin_amdgcn_sched_barrier(0);
  }

  // B2 frags load here; the gate VALU below covers their latency
  frag8 b2f[8];
#pragma unroll
  for (int i = 0; i < 8; ++i) b2f[i] = g2[i * 64 + lane];

  // gates from registers (packed-col): lane (m,q) -> rows 4q+r, channel 16b+m
#pragma unroll
  for (int b = 0; b < 3; ++b)
#pragma unroll
    for (int r = 0; r < 4; ++r) {
      float I = fsig(acc[3 * b][r]);
      float T = ftanh(acc[3 * b + 1][r]);
      float O = fsig(acc[3 * b + 2][r]);
      sHw[(q * 4 + r) * 72 + 16 * b + m] = f2bf(O * ftanh(I * T));
    }
  // channels 48,49 from acc[9] via shfl: c48 lanes 16q+{0,1,2}, c49 +{3,4,5}
#pragma unroll
  for (int r = 0; r < 4; ++r) {
    float vI = __shfl(acc[9][r], 16 * q + m);
    float vT = __shfl(acc[9][r], 16 * q + m + 1);
    float vO = __shfl(acc[9][r], 16 * q + m + 2);
    if (m == 0 || m == 3) {
      float I = fsig(vI), T = ftanh(vT), O = fsig(vO);
      sHw[(q * 4 + r) * 72 + 48 + (m >> 1)] = f2bf(O * ftanh(I * T));
    }
  }

  // ---- GEMM2: z2[16 x 64] = h1(bf16) @ B2h, K padded to 64 ----
  frag8 hh[2];
#pragma unroll
  for (int s = 0; s < 2; ++s)
    hh[s] = *(const frag8*)(sHw + m * 72 + 32 * s + 8 * q);
  fragC acc2[4];
#pragma unroll
  for (int t = 0; t < 4; ++t)
    acc2[t] = (fragC){bias2v[t], bias2v[t], bias2v[t], bias2v[t]};
#pragma unroll
  for (int s = 0; s < 2; ++s)
#pragma unroll
    for (int t = 0; t < 4; ++t)
      acc2[t] = __builtin_amdgcn_mfma_f32_16x16x32_bf16(hh[s], b2f[s * 4 + t], acc2[t], 0, 0, 0);

  // epilogue in registers: lane owns ch m (t=0,1,2) and (m<4) ch 16+m via shfl
  const float wlm = Wl[m];
  const float wlx = (m < 4) ? Wl[16 + m] : 0.f;
  const float blv = bl[0];
  v4f res;
#pragma unroll
  for (int r = 0; r < 4; ++r) {
    float I = fsig(acc2[0][r]);
    float T = ftanh(acc2[1][r]);
    float O = fsig(acc2[2][r]);
    float h2 = O * ftanh(I * T);
    float part = fmaxf(h2, 0.f) * wlm;
    float eI = __shfl(acc2[3][r], 16 * q + 3 * m);
    float eT = __shfl(acc2[3][r], 16 * q + 3 * m + 1);
    float eO = __shfl(acc2[3][r], 16 * q + 3 * m + 2);
    float I2 = fsig(eI), T2 = ftanh(eT), O2 = fsig(eO);
    float h2x = O2 * ftanh(I2 * T2);
    part += fmaxf(h2x, 0.f) * wlx;
    part += __shfl_xor(part, 1);
    part += __shfl_xor(part, 2);
    part += __shfl_xor(part, 4);
    part += __shfl_xor(part, 8);
    res[r] = part + blv;
  }
  if (m == 0) *(v4f*)(out + tau * 16 + 4 * q) = res;
}

extern "C" void kernel_launch(void* const* d_in, const int* in_sizes, int n_in,
                              void* d_out, int out_size, void* d_ws, size_t ws_size,
                              hipStream_t stream) {
  (void)in_sizes; (void)n_in; (void)out_size; (void)ws_size;
  const float* x = (const float*)d_in[0];
  // d_in[1] edge_index, d_in[2] edge_weight, d_in[5] theta1, d_in[9] theta2: dead
  const float* Wx1 = (const float*)d_in[3];
  const float* bx1 = (const float*)d_in[4];
  const float* bconv1 = (const float*)d_in[6];
  const float* Wx2 = (const float*)d_in[7];
  const float* bx2 = (const float*)d_in[8];
  const float* bconv2 = (const float*)d_in[10];
  const float* Wl = (const float*)d_in[11];
  const float* bl = (const float*)d_in[12];
  unsigned char* ws = (unsigned char*)d_ws;  // needs ~50 KB

  hipLaunchKernelGGL(pack_weights, dim3(32), dim3(256), 0, stream,
                     Wx1, bx1, bconv1, Wx2, bx2, bconv2, ws);
  hipLaunchKernelGGL(gclstm_main, dim3((NTILES + 3) / 4), dim3(256), 0, stream,
                     x, ws, Wl, bl, (float*)d_out);
}

// Round 10
// 128.817 us; speedup vs baseline: 1.0455x; 1.0071x over previous
//
#include <hip/hip_runtime.h>
#include <hip/hip_bf16.h>

// GCLSTM with H=C=None collapses to: gates from x@Wx only (conv = bconv const),
// forget gate dead, graph unused.
//   h1 = sig(zo)*tanh(sig(zi)*tanh(zc)),  z = x@Wx1[:,{i,c,o}] + bias
//   h2 = same with Wx2; out = relu(h2)@Wl + bl
//
// R10 vs R9 (R6..R9 all ~130-135 total; shfl tail is the last big shared
// serial chain: 24 __shfl + 16 serial __shfl_xor per wave on the DS pipe):
//  - ALL shfls removed. Gate triples that straddle lanes (ch48/49 of L1,
//    ch16..19 of L2) go through small per-wave LDS scratch (parallel tasks).
//  - Final relu(h2)@Wl via MFMA: products f32 -> pitch-36 LDS (2-way-conflict
//    free), read back as A-frags, hi/lo split, 2 MFMAs vs ones-B built in
//    registers (B[k][0]=1 for k<20). D lands in exact store layout.
//  - rest identical to R9: one-shot waves, L2 B-frags, pipelined GEMM1,
//    A bf16-hi, launch_bounds(256,2).

#define NODES 100000
#define NTILES 6250

typedef float v4f   __attribute__((ext_vector_type(4)));
typedef float fragC __attribute__((ext_vector_type(4)));
typedef short frag8 __attribute__((ext_vector_type(8)));

// ws byte offsets
#define OFF_B1H 0       // 40 frags * 1024 B
#define OFF_B2H 40960   // 8 frags * 1024 B
#define OFF_PB1 49152   // 160 f32 packed-col biases (layer1)
#define OFF_PB2 49792   // 64 f32 packed-col biases (layer2)

__device__ __forceinline__ unsigned short f2bf(float f) {
  unsigned int u = __float_as_uint(f);
  u += 0x7fffu + ((u >> 16) & 1u);  // RNE
  return (unsigned short)(u >> 16);
}
__device__ __forceinline__ float fsig(float z) {
  float t = __builtin_amdgcn_exp2f(z * -1.44269504088896f);
  return __builtin_amdgcn_rcpf(1.0f + t);
}
__device__ __forceinline__ float ftanh(float z) {
  float t = __builtin_amdgcn_exp2f(z * 2.88539008177793f);
  return 1.0f - 2.0f * __builtin_amdgcn_rcpf(t + 1.0f);
}

union bfu { __hip_bfloat162 h; unsigned int u; };

__device__ __forceinline__ frag8 cvt8hi(const float* v) {
  frag8 hi;
#pragma unroll
  for (int p = 0; p < 4; ++p) {
    bfu c; c.h = __float22bfloat162_rn(make_float2(v[2 * p], v[2 * p + 1]));
    hi[2 * p]     = (short)(c.u & 0xffffu);
    hi[2 * p + 1] = (short)(c.u >> 16);
  }
  return hi;
}
__device__ __forceinline__ void cvt8(const float* v, frag8& hi, frag8& lo) {
  float lof[8];
#pragma unroll
  for (int p = 0; p < 4; ++p) {
    bfu c; c.h = __float22bfloat162_rn(make_float2(v[2 * p], v[2 * p + 1]));
    hi[2 * p]     = (short)(c.u & 0xffffu);
    hi[2 * p + 1] = (short)(c.u >> 16);
    lof[2 * p]     = v[2 * p]     - __uint_as_float((c.u & 0xffffu) << 16);
    lof[2 * p + 1] = v[2 * p + 1] - __uint_as_float(c.u & 0xffff0000u);
  }
#pragma unroll
  for (int p = 0; p < 4; ++p) {
    bfu c; c.h = __float22bfloat162_rn(make_float2(lof[2 * p], lof[2 * p + 1]));
    lo[2 * p]     = (short)(c.u & 0xffffu);
    lo[2 * p + 1] = (short)(c.u >> 16);
  }
}

// B1 packed-col: col = 16t+m.  t<=8: g=t%3, c=16*(t/3)+m.
// t==9: m<6 -> c=48+m/3, g=m%3; else pad.  g {i,c,o} -> Wx1 col {0,2,3}.
// B2 packed-col: col = 16t+m.  t<=2: g=t, c=m.
// t==3: m<12 -> c=16+m/3, g=m%3; else pad.  g -> Wx2 col {0,2,3}.
__global__ void pack_weights(const float* __restrict__ Wx1, const float* __restrict__ bx1,
                             const float* __restrict__ bconv1,
                             const float* __restrict__ Wx2, const float* __restrict__ bx2,
                             const float* __restrict__ bconv2,
                             unsigned char* __restrict__ ws) {
  const int tid = blockIdx.x * blockDim.x + threadIdx.x;
  const int stride = gridDim.x * blockDim.x;
  unsigned short* B1H = (unsigned short*)(ws + OFF_B1H);
  unsigned short* B2H = (unsigned short*)(ws + OFF_B2H);
  float* PB1 = (float*)(ws + OFF_PB1);
  float* PB2 = (float*)(ws + OFF_PB2);

  for (int idx = tid; idx < 20480; idx += stride) {
    int j = idx & 7, lane = (idx >> 3) & 63, ft = idx >> 9;  // ft = s*10+t
    int s = ft / 10, t = ft % 10;
    int k = 32 * s + ((lane >> 4) << 3) + j;
    int m = lane & 15;
    int c = -1, g = 0;
    if (t <= 8) { g = t % 3; c = 16 * (t / 3) + m; }
    else if (m < 6) { c = 48 + m / 3; g = m % 3; }
    float val = 0.f;
    if (c >= 0) {
      int gs = (g == 0) ? 0 : (g == 1) ? 2 : 3;
      val = Wx1[k * 200 + gs * 50 + c];
    }
    B1H[idx] = f2bf(val);
  }
  for (int idx = tid; idx < 4096; idx += stride) {
    int j = idx & 7, lane = (idx >> 3) & 63, ft = idx >> 9;  // ft = s*4+t
    int s = ft >> 2, t = ft & 3;
    int k = 32 * s + ((lane >> 4) << 3) + j;
    int m = lane & 15;
    int c = -1, g = 0;
    if (t <= 2) { g = t; c = m; }
    else if (m < 12) { c = 16 + m / 3; g = m % 3; }
    float val = 0.f;
    if (c >= 0 && k < 50) {
      int gs = (g == 0) ? 0 : (g == 1) ? 2 : 3;
      val = Wx2[k * 80 + gs * 20 + c];
    }
    B2H[idx] = f2bf(val);
  }
  for (int idx = tid; idx < 160; idx += stride) {
    int t = idx >> 4, m = idx & 15;
    int c = -1, g = 0;
    if (t <= 8) { g = t % 3; c = 16 * (t / 3) + m; }
    else if (m < 6) { c = 48 + m / 3; g = m % 3; }
    float v = 0.f;
    if (c >= 0) {
      int gs = (g == 0) ? 0 : (g == 1) ? 2 : 3;
      v = bx1[gs * 50 + c] + bconv1[gs * 50 + c];
    }
    PB1[idx] = v;
  }
  for (int idx = tid; idx < 64; idx += stride) {
    int t = idx >> 4, m = idx & 15;
    int c = -1, g = 0;
    if (t <= 2) { g = t; c = m; }
    else if (m < 12) { c = 16 + m / 3; g = m % 3; }
    float v = 0.f;
    if (c >= 0) {
      int gs = (g == 0) ? 0 : (g == 1) ? 2 : 3;
      v = bx2[gs * 20 + c] + bconv2[gs * 20 + c];
    }
    PB2[idx] = v;
  }
}

__global__ __launch_bounds__(256, 2) void gclstm_main(
    const float* __restrict__ x, const unsigned char* __restrict__ wsb,
    const float* __restrict__ Wl, const float* __restrict__ bl,
    float* __restrict__ out) {
  __shared__ unsigned short sH[4][16 * 72];  //  9216 B: per-wave h1 (bf16)
  __shared__ float sP[4][16 * 36];           //  9216 B: per-wave Wl-products f32
  __shared__ float sT[4][16 * 12];           //  3072 B: per-wave gate-triple scratch

  const int tid = threadIdx.x;
  const int lane = tid & 63;
  const int wave = tid >> 6;
  const int m = lane & 15;
  const int q = lane >> 4;
  const int tau = blockIdx.x * 4 + wave;  // this wave's tile
  if (tau >= NTILES) return;              // no barriers anywhere -> safe

  unsigned short* sHw = (unsigned short*)sH + wave * (16 * 72);
  float* sPw = (float*)sP + wave * (16 * 36);
  float* sTw = (float*)sT + wave * (16 * 12);

  // zero K-pad cols 48..63 of h1 rows (48,49 overwritten below)
  {
    int r0 = lane >> 2, c0 = 48 + (lane & 3) * 4;
    *(unsigned long long*)(sHw + r0 * 72 + c0) = 0ull;
  }
  // zero product cols 20..31 (K-pad of the final MFMA)
#pragma unroll
  for (int i = 0; i < 3; ++i) {
    int idx = lane * 3 + i;
    sPw[(idx / 12) * 36 + 20 + idx % 12] = 0.f;
  }

  // x rows: lane m -> row, quad q -> k-octet base (issue first, deepest miss)
  const float* xr = x + (size_t)(tau * 16 + m) * 128 + q * 8;
  v4f xb[8];
#pragma unroll
  for (int s = 0; s < 4; ++s) {
    xb[2 * s] = *(const v4f*)(xr + 32 * s);
    xb[2 * s + 1] = *(const v4f*)(xr + 32 * s + 4);
  }

  // per-lane biases from L2 (packed-col order)
  const float* pb1 = (const float*)(wsb + OFF_PB1);
  const float* pb2 = (const float*)(wsb + OFF_PB2);
  float bias1v[10], bias2v[4];
#pragma unroll
  for (int t = 0; t < 10; ++t) bias1v[t] = pb1[16 * t + m];
#pragma unroll
  for (int t = 0; t < 4; ++t) bias2v[t] = pb2[16 * t + m];

  const frag8* g1 = (const frag8*)(wsb + OFF_B1H);
  const frag8* g2 = (const frag8*)(wsb + OFF_B2H);

  // stage-0 B frags
  frag8 ba[10], bb[10];
#pragma unroll
  for (int t = 0; t < 10; ++t) ba[t] = g1[t * 64 + lane];

  // A -> bf16 (hi only)
  frag8 ah[4];
#pragma unroll
  for (int s = 0; s < 4; ++s) {
    float av[8];
    *(v4f*)av = xb[2 * s];
    *(v4f*)(av + 4) = xb[2 * s + 1];
    ah[s] = cvt8hi(av);
  }

  // ---- GEMM1: z1[16 x 160] = A @ B1, software-pipelined B double-buffer ----
  fragC acc[10];
#pragma unroll
  for (int t = 0; t < 10; ++t)
    acc[t] = (fragC){bias1v[t], bias1v[t], bias1v[t], bias1v[t]};
#pragma unroll
  for (int s = 0; s < 4; ++s) {
    frag8* bc = (s & 1) ? bb : ba;
    frag8* bn = (s & 1) ? ba : bb;
    if (s < 3) {  // issue next stage's loads ahead of this stage's MFMAs
#pragma unroll
      for (int t = 0; t < 10; ++t) bn[t] = g1[((s + 1) * 10 + t) * 64 + lane];
    }
#pragma unroll
    for (int t = 0; t < 10; ++t)
      acc[t] = __builtin_amdgcn_mfma_f32_16x16x32_bf16(ah[s], bc[t], acc[t], 0, 0, 0);
    // stage fence: caps hoisting at one extra buffer (2x40 frag regs max);
    // without it the scheduler lifts everything -> R4/R5's spill storm
    __builtin_amdgcn_sched_barrier(0);
  }

  // B2 frags load here; the gate VALU below covers their latency
  frag8 b2f[8];
#pragma unroll
  for (int i = 0; i < 8; ++i) b2f[i] = g2[i * 64 + lane];

  // gates from registers (packed-col): lane (m,q) -> rows 4q+r, channel 16b+m
#pragma unroll
  for (int b = 0; b < 3; ++b)
#pragma unroll
    for (int r = 0; r < 4; ++r) {
      float I = fsig(acc[3 * b][r]);
      float T = ftanh(acc[3 * b + 1][r]);
      float O = fsig(acc[3 * b + 2][r]);
      sHw[(q * 4 + r) * 72 + 16 * b + m] = f2bf(O * ftanh(I * T));
    }
  // channels 48,49 via LDS scratch (no shfl): acc[9] cols 0..5 hold the triples
  if (m < 6) {
#pragma unroll
    for (int r = 0; r < 4; ++r) sTw[(q * 4 + r) * 6 + m] = acc[9][r];
  }
  {
    int row = lane & 15, cc = lane >> 4;
    if (cc < 2) {  // 32 parallel tasks: (row, channel 48+cc)
      float I = fsig(sTw[row * 6 + 3 * cc]);
      float T = ftanh(sTw[row * 6 + 3 * cc + 1]);
      float O = fsig(sTw[row * 6 + 3 * cc + 2]);
      sHw[row * 72 + 48 + cc] = f2bf(O * ftanh(I * T));
    }
  }

  // ---- GEMM2: z2[16 x 64] = h1(bf16) @ B2h, K padded to 64 ----
  frag8 hh[2];
#pragma unroll
  for (int s = 0; s < 2; ++s)
    hh[s] = *(const frag8*)(sHw + m * 72 + 32 * s + 8 * q);
  fragC acc2[4];
#pragma unroll
  for (int t = 0; t < 4; ++t)
    acc2[t] = (fragC){bias2v[t], bias2v[t], bias2v[t], bias2v[t]};
#pragma unroll
  for (int s = 0; s < 2; ++s)
#pragma unroll
    for (int t = 0; t < 4; ++t)
      acc2[t] = __builtin_amdgcn_mfma_f32_16x16x32_bf16(hh[s], b2f[s * 4 + t], acc2[t], 0, 0, 0);

  // layer-2 gates -> relu(h2)*Wl products into sP (f32, pitch 36)
  const float wlm = Wl[m];
  const float wlc = Wl[16 + q];
#pragma unroll
  for (int r = 0; r < 4; ++r) {  // lane owns channel m for rows 4q+r
    float I = fsig(acc2[0][r]);
    float T = ftanh(acc2[1][r]);
    float O = fsig(acc2[2][r]);
    float h2 = O * ftanh(I * T);
    sPw[(q * 4 + r) * 36 + m] = fmaxf(h2, 0.f) * wlm;
  }
  // channels 16..19 via LDS scratch (acc2[3] cols 0..11 hold the triples)
  if (m < 12) {
#pragma unroll
    for (int r = 0; r < 4; ++r) sTw[(q * 4 + r) * 12 + m] = acc2[3][r];
  }
  {
    int row = lane & 15, cc = lane >> 4;  // 64 parallel tasks
    float I = fsig(sTw[row * 12 + 3 * cc]);
    float T = ftanh(sTw[row * 12 + 3 * cc + 1]);
    float O = fsig(sTw[row * 12 + 3 * cc + 2]);
    float h2 = O * ftanh(I * T);
    sPw[row * 36 + 16 + cc] = fmaxf(h2, 0.f) * wlc;
  }

  // ---- final dot via MFMA: D[row][0] = sum_k prod[row][k] * 1_{k<20} ----
  float pv[8];
  *(v4f*)pv       = *(const v4f*)(sPw + m * 36 + q * 8);
  *(v4f*)(pv + 4) = *(const v4f*)(sPw + m * 36 + q * 8 + 4);
  frag8 pa, pl;
  cvt8(pv, pa, pl);  // hi/lo split keeps fp32-grade accuracy
  frag8 bw;          // ones-vector B: B[k = 8q+j][n = m] = (m==0 && k<20)
#pragma unroll
  for (int j = 0; j < 8; ++j)
    bw[j] = (short)((m == 0 && (8 * q + j) < 20) ? 0x3F80 : 0);
  fragC acco = (fragC){0.f, 0.f, 0.f, 0.f};
  acco = __builtin_amdgcn_mfma_f32_16x16x32_bf16(pa, bw, acco, 0, 0, 0);
  acco = __builtin_amdgcn_mfma_f32_16x16x32_bf16(pl, bw, acco, 0, 0, 0);

  if (m == 0) {  // col 0 lives on lanes 16q; row = 4q+r
    const float blv = bl[0];
    v4f res;
#pragma unroll
    for (int r = 0; r < 4; ++r) res[r] = acco[r] + blv;
    *(v4f*)(out + tau * 16 + 4 * q) = res;
  }
}

extern "C" void kernel_launch(void* const* d_in, const int* in_sizes, int n_in,
                              void* d_out, int out_size, void* d_ws, size_t ws_size,
                              hipStream_t stream) {
  (void)in_sizes; (void)n_in; (void)out_size; (void)ws_size;
  const float* x = (const float*)d_in[0];
  // d_in[1] edge_index, d_in[2] edge_weight, d_in[5] theta1, d_in[9] theta2: dead
  const float* Wx1 = (const float*)d_in[3];
  const float* bx1 = (const float*)d_in[4];
  const float* bconv1 = (const float*)d_in[6];
  const float* Wx2 = (const float*)d_in[7];
  const float* bx2 = (const float*)d_in[8];
  const float* bconv2 = (const float*)d_in[10];
  const float* Wl = (const float*)d_in[11];
  const float* bl = (const float*)d_in[12];
  unsigned char* ws = (unsigned char*)d_ws;  // needs ~50 KB

  hipLaunchKernelGGL(pack_weights, dim3(32), dim3(256), 0, stream,
                     Wx1, bx1, bconv1, Wx2, bx2, bconv2, ws);
  hipLaunchKernelGGL(gclstm_main, dim3((NTILES + 3) / 4), dim3(256), 0, stream,
                     x, ws, Wl, bl, (float*)d_out);
}